// Round 4
// baseline (9029.889 us; speedup 1.0000x reference)
//
#include <hip/hip_runtime.h>
#include <math.h>

using f16x8 = __attribute__((ext_vector_type(8))) _Float16;
using f32x4 = __attribute__((ext_vector_type(4))) float;

// ---------------- problem constants ----------------
constexpr int Tst  = 60;
constexpr int ROWS = 32;            // batch rows per block (N = 2 x 16)
constexpr int NBLK = 2048 / ROWS;   // 64 blocks
constexpr int NTHR = 512;           // 8 waves

// ---------------- workspace: fp16 hi/lo fragment streams (u16 elems) ----------------
// Fragment = 64 lanes x 8 f16 = 512 u16 = 1KB. M-order: m = unit*4 + gate.
// A-frag element (lane,j): m = mt*16 + (lane&15), k_in = (lane>>4)*8 + j  [sigma, used on BOTH A and B]
// AG0[mt=64][kt=9][s=2]  : context->gates W_ih0[:,2:258]; kt8 = bias(b_ih0+b_hh0) ones-col
// AL0[mt=64][kt=9][s=2]  : W_hh0; kt8 = pos cols (W_ih0[:,0:2])
// AL1[mt=64][kt=17][s=2] : kt0-7 W_ih1, kt8-15 W_hh1, kt16 = bias(b_ih1+b_hh1) ones-col
// AH1[mt=4][kt=9][s=2]   : W_out1; kt8 = b_out1 ones-col
constexpr int FR     = 512;
constexpr int N_AG0  = 64 * 9  * 2 * FR;
constexpr int N_AL0  = 64 * 9  * 2 * FR;
constexpr int N_AL1  = 64 * 17 * 2 * FR;
constexpr int N_AH1  = 4  * 9  * 2 * FR;
constexpr int OFF_AG0 = 0;
constexpr int OFF_AL0 = OFF_AG0 + N_AG0;      //   589,824
constexpr int OFF_AL1 = OFF_AL0 + N_AL0;      // 1,179,648
constexpr int OFF_AH1 = OFF_AL1 + N_AL1;      // 2,293,760
constexpr int WS_U16  = OFF_AH1 + N_AH1;      // 2,330,624 u16 = 4,661,248 B (<= provided ws)

__device__ __forceinline__ unsigned short hbits(_Float16 h) {
    union { _Float16 h; unsigned short u; } x; x.h = h; return x.u;
}

// ---------------- weight repack: fp16 hi/lo split into fragment streams ----------------
__global__ void prep_kernel(const float* __restrict__ Wih0, const float* __restrict__ Whh0,
                            const float* __restrict__ bih0, const float* __restrict__ bhh0,
                            const float* __restrict__ Wih1, const float* __restrict__ Whh1,
                            const float* __restrict__ bih1, const float* __restrict__ bhh1,
                            const float* __restrict__ Wout1, const float* __restrict__ bout1,
                            unsigned short* __restrict__ ws) {
    int i = blockIdx.x * 256 + threadIdx.x;
    if (i >= WS_U16) return;
    int arr, idx = i, KT;
    if (i < OFF_AL0)      { arr = 0; KT = 9; }
    else if (i < OFF_AL1) { arr = 1; idx -= OFF_AL0; KT = 9; }
    else if (i < OFF_AH1) { arr = 2; idx -= OFF_AL1; KT = 17; }
    else                  { arr = 3; idx -= OFF_AH1; KT = 9; }
    const int per_mt = KT * 2 * FR;
    const int mt = idx / per_mt;
    int r = idx - mt * per_mt;
    const int kt = r / (2 * FR);
    r -= kt * 2 * FR;
    const int s    = r >> 9;            // 0 = hi, 1 = lo
    const int f    = r & 511;
    const int lane = f >> 3, j = f & 7;
    const int m    = mt * 16 + (lane & 15);
    const int k_in = ((lane >> 4) << 3) + j;

    float v = 0.f;
    if (arr == 3) {                                   // AH1 (m = mlp index 0..63)
        if (kt < 8) v = Wout1[m * 256 + kt * 32 + k_in];
        else if (k_in == 0) v = bout1[m];
    } else {
        const int unit = m >> 2, gate = m & 3, row = gate * 256 + unit;
        if (arr == 0) {                               // AG0
            if (kt < 8) v = Wih0[row * 258 + 2 + kt * 32 + k_in];
            else if (k_in == 0) v = bih0[row] + bhh0[row];
        } else if (arr == 1) {                        // AL0
            if (kt < 8) v = Whh0[row * 256 + kt * 32 + k_in];
            else if (k_in < 2) v = Wih0[row * 258 + k_in];
        } else {                                      // AL1
            if (kt < 8)         v = Wih1[row * 256 + kt * 32 + k_in];
            else if (kt < 16)   v = Whh1[row * 256 + (kt - 8) * 32 + k_in];
            else if (k_in == 0) v = bih1[row] + bhh1[row];
        }
    }
    _Float16 hi = (_Float16)v;
    ws[i] = (s == 0) ? hbits(hi) : hbits((_Float16)(v - (float)hi));
}

// ---------------- helpers ----------------
__device__ __forceinline__ f32x4 MF(f16x8 a, f16x8 b, f32x4 c) {
    return __builtin_amdgcn_mfma_f32_16x16x32_f16(a, b, c, 0, 0, 0);
}
__device__ __forceinline__ float sigm(float x) { return 1.f / (1.f + __expf(-x)); }
__device__ __forceinline__ float tanh_(float x) {
    float e = __expf(-2.f * fabsf(x));
    float r = (1.f - e) / (1.f + e);
    return copysignf(r, x);
}

// ---------------- main kernel ----------------
// 512 thr = 8 waves; wave w owns units [w*32, w*32+32) => M-tiles mt = w*8+mm.
// LDS hb[s][nt][slot][512]: slots 0-7 h1, 8-15 h2, 16 ones(+bias), 17 pos.
__global__ __launch_bounds__(NTHR, 2) void lstm_main(
    const float* __restrict__ env, const float* __restrict__ hist,
    const float* __restrict__ goal, const float* __restrict__ cpos,
    const float* __restrict__ Wproj, const float* __restrict__ b_proj,
    const float* __restrict__ Wout2, const float* __restrict__ b_out2,
    const unsigned short* __restrict__ ws, float* __restrict__ out) {

    __shared__ __align__(16) _Float16 hb[2][2][18][512];   // 73,728 B
    __shared__ __align__(16) float scratch[386 * 32];      // 49,408 B (xbuf, then mlp overlay)

    const int t = threadIdx.x;
    const int w = t >> 6;
    const int l = t & 63;
    const int row0 = (int)blockIdx.x * ROWS;

    float* xbuf = scratch;     // [386][32] (prologue)
    float* mlpL = scratch;     // [32][68]  (step loop)

    // ---- P1: stage ctx_in [k][r] ----
    for (int idx = t; idx < 386 * 32; idx += NTHR) {
        int r = idx & 31, k = idx >> 5;
        int gr = row0 + r; float v;
        if (k < 256)      v = env[gr * 256 + k];
        else if (k < 384) v = hist[gr * 128 + (k - 256)];
        else              v = goal[gr * 2 + (k - 384)];
        xbuf[k * 32 + r] = v;
    }
    // ---- P2: ones-slot(16) + pos-slot(17) ----
    for (int idx = t; idx < 4096; idx += NTHR) {
        int f = idx & 511, sl = (idx >> 9) & 1, nt = (idx >> 10) & 1, s = idx >> 11;
        int lane = f >> 3, j = f & 7;
        int k_in = ((lane >> 4) << 3) + j;
        float v = 0.f;
        if (sl == 0) {                       // ones slot
            if (s == 0 && k_in == 0) v = 1.f;
        } else if (k_in < 2) {               // pos slot: k 0,1 = pos x,y
            float pv = cpos[(row0 + nt * 16 + (lane & 15)) * 2 + k_in];
            _Float16 hi = (_Float16)pv;
            v = (s == 0) ? (float)hi : (pv - (float)hi);
        }
        hb[s][nt][16 + sl][f] = (_Float16)v;
    }
    __syncthreads();

    // ---- P3: context = ctx_in @ Wproj.T + b_proj (fp32) -> h1/h2 frag init ----
    {
        const int u = t & 255, rh = t >> 8;
        float acc[16];
        float bp = b_proj[u];
#pragma unroll
        for (int rr = 0; rr < 16; ++rr) acc[rr] = bp;
        for (int k = 0; k < 386; ++k) {
            float wv = Wproj[u * 386 + k];
            const float* xr = &xbuf[k * 32 + rh * 16];
#pragma unroll
            for (int rr = 0; rr < 16; ++rr) acc[rr] = fmaf(xr[rr], wv, acc[rr]);
        }
        const int kt = u >> 5, k_in = u & 31;
        const int fb = 16 * (k_in >> 3) * 8 + (k_in & 7);
#pragma unroll
        for (int rr = 0; rr < 16; ++rr) {
            float v = acc[rr];
            _Float16 hi = (_Float16)v, lo = (_Float16)(v - (float)hi);
            int f = fb + rr * 8;
            hb[0][rh][kt][f] = hi;      hb[1][rh][kt][f] = lo;
            hb[0][rh][8 + kt][f] = hi;  hb[1][rh][8 + kt][f] = lo;
        }
    }
    __syncthreads();

    // ---- P4: G0c (ctx contribution + L0 biases) via MFMA, kept in registers ----
    f32x4 G0[8][2];
#pragma unroll
    for (int m = 0; m < 8; ++m) {
        G0[m][0] = f32x4{0.f, 0.f, 0.f, 0.f};
        G0[m][1] = f32x4{0.f, 0.f, 0.f, 0.f};
    }
    {
        const unsigned short* A = ws + OFF_AG0 + (w * 8) * (9 * 1024) + l * 8;
        for (int kt = 0; kt < 9; ++kt) {
            const int slot = (kt < 8) ? kt : 16;
            f16x8 b00 = *(const f16x8*)&hb[0][0][slot][l * 8];
            f16x8 b01 = *(const f16x8*)&hb[0][1][slot][l * 8];
            f16x8 b10 = *(const f16x8*)&hb[1][0][slot][l * 8];
            f16x8 b11 = *(const f16x8*)&hb[1][1][slot][l * 8];
#pragma unroll
            for (int mm = 0; mm < 8; ++mm) {
                const unsigned short* p = A + (mm * 9 + kt) * 1024;
                f16x8 ah = *(const f16x8*)p;
                f16x8 al = *(const f16x8*)(p + 512);
                G0[mm][0] = MF(ah, b00, G0[mm][0]);
                G0[mm][0] = MF(ah, b10, G0[mm][0]);
                G0[mm][0] = MF(al, b00, G0[mm][0]);
                G0[mm][1] = MF(ah, b01, G0[mm][1]);
                G0[mm][1] = MF(ah, b11, G0[mm][1]);
                G0[mm][1] = MF(al, b01, G0[mm][1]);
            }
        }
    }

    float c1[8][2], c2[8][2];
#pragma unroll
    for (int m = 0; m < 8; ++m) { c1[m][0] = c1[m][1] = c2[m][0] = c2[m][1] = 0.f; }

    const unsigned short* AL0 = ws + OFF_AL0 + (w * 8) * (9 * 1024) + l * 8;
    const unsigned short* AL1 = ws + OFF_AL1 + (w * 8) * (17 * 1024) + l * 8;
    const unsigned short* AH1 = ws + OFF_AH1 + (w & 3) * (9 * 1024) + l * 8;
    const int hnt = w >> 2;

    // ================= time loop =================
    for (int st = 0; st < Tst; ++st) {
        // ===== L0: gates = G0c + pos@Wp + h1@Whh0 =====
        f32x4 acc[8][2];
#pragma unroll
        for (int m = 0; m < 8; ++m) { acc[m][0] = G0[m][0]; acc[m][1] = G0[m][1]; }
        for (int kt = 0; kt < 9; ++kt) {
            const int slot = (kt < 8) ? kt : 17;
            f16x8 b00 = *(const f16x8*)&hb[0][0][slot][l * 8];
            f16x8 b01 = *(const f16x8*)&hb[0][1][slot][l * 8];
            f16x8 b10 = *(const f16x8*)&hb[1][0][slot][l * 8];
            f16x8 b11 = *(const f16x8*)&hb[1][1][slot][l * 8];
#pragma unroll
            for (int mm = 0; mm < 8; ++mm) {
                const unsigned short* p = AL0 + (mm * 9 + kt) * 1024;
                f16x8 ah = *(const f16x8*)p;
                f16x8 al = *(const f16x8*)(p + 512);
                acc[mm][0] = MF(ah, b00, acc[mm][0]);
                acc[mm][0] = MF(ah, b10, acc[mm][0]);
                acc[mm][0] = MF(al, b00, acc[mm][0]);
                acc[mm][1] = MF(ah, b01, acc[mm][1]);
                acc[mm][1] = MF(ah, b11, acc[mm][1]);
                acc[mm][1] = MF(al, b01, acc[mm][1]);
            }
        }
        float h1n[8][2];
#pragma unroll
        for (int mm = 0; mm < 8; ++mm)
#pragma unroll
            for (int nt = 0; nt < 2; ++nt) {
                f32x4 g = acc[mm][nt];
                float iv = sigm(g[0]), fv = sigm(g[1]);
                float gv = tanh_(g[2]), ov = sigm(g[3]);
                float c = fmaf(fv, c1[mm][nt], iv * gv);
                c1[mm][nt] = c;
                h1n[mm][nt] = ov * tanh_(c);
            }
        __syncthreads();   // all waves done reading h1_old + pos
#pragma unroll
        for (int mm = 0; mm < 8; ++mm) {
            const int k_in = mm * 4 + (l >> 4);
            const int f = ((l & 15) + 16 * (k_in >> 3)) * 8 + (k_in & 7);
#pragma unroll
            for (int nt = 0; nt < 2; ++nt) {
                float v = h1n[mm][nt];
                _Float16 hi = (_Float16)v, lo = (_Float16)(v - (float)hi);
                hb[0][nt][w][f] = hi;
                hb[1][nt][w][f] = lo;
            }
        }
        __syncthreads();   // h1_new visible

        // ===== L1: gates = b1 + h1_new@Wih1 + h2_old@Whh1 =====
#pragma unroll
        for (int m = 0; m < 8; ++m) {
            acc[m][0] = f32x4{0.f, 0.f, 0.f, 0.f};
            acc[m][1] = f32x4{0.f, 0.f, 0.f, 0.f};
        }
        for (int kt = 0; kt < 17; ++kt) {
            const int slot = kt;   // 0-15 = h1,h2 ; 16 = ones (bias)
            f16x8 b00 = *(const f16x8*)&hb[0][0][slot][l * 8];
            f16x8 b01 = *(const f16x8*)&hb[0][1][slot][l * 8];
            f16x8 b10 = *(const f16x8*)&hb[1][0][slot][l * 8];
            f16x8 b11 = *(const f16x8*)&hb[1][1][slot][l * 8];
#pragma unroll
            for (int mm = 0; mm < 8; ++mm) {
                const unsigned short* p = AL1 + (mm * 17 + kt) * 1024;
                f16x8 ah = *(const f16x8*)p;
                f16x8 al = *(const f16x8*)(p + 512);
                acc[mm][0] = MF(ah, b00, acc[mm][0]);
                acc[mm][0] = MF(ah, b10, acc[mm][0]);
                acc[mm][0] = MF(al, b00, acc[mm][0]);
                acc[mm][1] = MF(ah, b01, acc[mm][1]);
                acc[mm][1] = MF(ah, b11, acc[mm][1]);
                acc[mm][1] = MF(al, b01, acc[mm][1]);
            }
        }
        float h2n[8][2];
#pragma unroll
        for (int mm = 0; mm < 8; ++mm)
#pragma unroll
            for (int nt = 0; nt < 2; ++nt) {
                f32x4 g = acc[mm][nt];
                float iv = sigm(g[0]), fv = sigm(g[1]);
                float gv = tanh_(g[2]), ov = sigm(g[3]);
                float c = fmaf(fv, c2[mm][nt], iv * gv);
                c2[mm][nt] = c;
                h2n[mm][nt] = ov * tanh_(c);
            }
        __syncthreads();   // all waves done reading h2_old
#pragma unroll
        for (int mm = 0; mm < 8; ++mm) {
            const int k_in = mm * 4 + (l >> 4);
            const int f = ((l & 15) + 16 * (k_in >> 3)) * 8 + (k_in & 7);
#pragma unroll
            for (int nt = 0; nt < 2; ++nt) {
                float v = h2n[mm][nt];
                _Float16 hi = (_Float16)v, lo = (_Float16)(v - (float)hi);
                hb[0][nt][8 + w][f] = hi;
                hb[1][nt][8 + w][f] = lo;
            }
        }
        __syncthreads();   // h2_new visible

        // ===== head1: mlp = relu(h2 @ Wout1.T + b_out1); wave w -> (mt=w&3, nt=w>>2) =====
        {
            f32x4 pa = {0.f, 0.f, 0.f, 0.f}, pb = {0.f, 0.f, 0.f, 0.f};
#pragma unroll
            for (int kt = 0; kt < 9; ++kt) {
                const int slot = (kt < 8) ? (8 + kt) : 16;
                f16x8 bh = *(const f16x8*)&hb[0][hnt][slot][l * 8];
                f16x8 bl = *(const f16x8*)&hb[1][hnt][slot][l * 8];
                const unsigned short* p = AH1 + kt * 1024;
                f16x8 ah = *(const f16x8*)p;
                f16x8 al = *(const f16x8*)(p + 512);
                if (kt & 1) { pb = MF(ah, bh, pb); pb = MF(ah, bl, pb); pb = MF(al, bh, pb); }
                else        { pa = MF(ah, bh, pa); pa = MF(ah, bl, pa); pa = MF(al, bh, pa); }
            }
            f32x4 pv = pa + pb;
#pragma unroll
            for (int r = 0; r < 4; ++r) pv[r] = fmaxf(pv[r], 0.f);
            const int mrow = hnt * 16 + (l & 15);
            float* mp = &mlpL[mrow * 68 + (w & 3) * 16 + (l >> 4) * 4];
            *(f32x4*)mp = pv;
        }
        __syncthreads();

        // ===== head2: pred = mlp @ Wout2.T + b_out2 (fp32); pos feedback =====
        if (t < 64) {
            const int r = t >> 1, o = t & 1;
            float a = b_out2[o];
#pragma unroll 8
            for (int k = 0; k < 64; ++k) a = fmaf(mlpL[r * 68 + k], Wout2[o * 64 + k], a);
            out[((size_t)(row0 + r) * Tst + st) * 2 + o] = a;
            _Float16 hi = (_Float16)a, lo = (_Float16)(a - (float)hi);
            hb[0][r >> 4][17][(r & 15) * 8 + o] = hi;
            hb[1][r >> 4][17][(r & 15) * 8 + o] = lo;
        }
        __syncthreads();
    }
}

// ---------------- launch ----------------
extern "C" void kernel_launch(void* const* d_in, const int* in_sizes, int n_in,
                              void* d_out, int out_size, void* d_ws, size_t ws_size,
                              hipStream_t stream) {
    const float* env   = (const float*)d_in[0];
    const float* hist  = (const float*)d_in[1];
    const float* goal  = (const float*)d_in[2];
    const float* cpos  = (const float*)d_in[3];
    const float* Wproj = (const float*)d_in[4];
    const float* bproj = (const float*)d_in[5];
    const float* Wih0  = (const float*)d_in[6];
    const float* Whh0  = (const float*)d_in[7];
    const float* bih0  = (const float*)d_in[8];
    const float* bhh0  = (const float*)d_in[9];
    const float* Wih1  = (const float*)d_in[10];
    const float* Whh1  = (const float*)d_in[11];
    const float* bih1  = (const float*)d_in[12];
    const float* bhh1  = (const float*)d_in[13];
    const float* Wout1 = (const float*)d_in[14];
    const float* bout1 = (const float*)d_in[15];
    const float* Wout2 = (const float*)d_in[16];
    const float* bout2 = (const float*)d_in[17];

    if (ws_size < (size_t)WS_U16 * 2) return;
    unsigned short* ws = (unsigned short*)d_ws;

    prep_kernel<<<(WS_U16 + 255) / 256, 256, 0, stream>>>(
        Wih0, Whh0, bih0, bhh0, Wih1, Whh1, bih1, bhh1, Wout1, bout1, ws);

    lstm_main<<<NBLK, NTHR, 0, stream>>>(
        env, hist, goal, cpos, Wproj, bproj, Wout2, bout2, ws, (float*)d_out);
}

// Round 5
// 1921.817 us; speedup vs baseline: 4.6986x; 4.6986x over previous
//
#include <hip/hip_runtime.h>
#include <math.h>

using f16x8 = __attribute__((ext_vector_type(8))) _Float16;
using f32x4 = __attribute__((ext_vector_type(4))) float;
using u16   = unsigned short;

// ---------------- problem constants ----------------
constexpr int Tst = 60;

// ---------------- workspace: A-fragment streams (identical layout to round 4) ----
constexpr int FR      = 512;
constexpr int N_AG0   = 64 * 9  * 2 * FR;
constexpr int N_AL0   = 64 * 9  * 2 * FR;
constexpr int N_AL1   = 64 * 17 * 2 * FR;
constexpr int N_AH1   = 4  * 9  * 2 * FR;
constexpr int OFF_AG0 = 0;
constexpr int OFF_AL0 = OFF_AG0 + N_AG0;
constexpr int OFF_AL1 = OFF_AL0 + N_AL0;
constexpr int OFF_AH1 = OFF_AL1 + N_AL1;
constexpr int WS_U16  = OFF_AH1 + N_AH1;          // 2,330,624 u16

// ---------------- h-exchange slabs + flags ----------------
// H[bc 64][par 2][layer 2] slab of [kt 8][s 2][nt 2][512] u16 (B-fragment layout)
constexpr int N_HSLAB = 8 * 2 * 2 * 512;          // 16384 u16 = 32 KB
constexpr int OFF_H   = WS_U16;
constexpr int N_H     = 64 * 2 * 2 * N_HSLAB;     // 4,194,304 u16
constexpr int OFF_FLG = OFF_H + N_H;              // flags (int) at byte off OFF_FLG*2
constexpr int N_FLAGS = 64 * 2 * 4;               // [bc][layer][uc]
constexpr size_t WS_BYTES = (size_t)OFF_FLG * 2 + (size_t)N_FLAGS * sizeof(int);

__device__ __forceinline__ u16 hbits(_Float16 h) {
    union { _Float16 h; u16 u; } x; x.h = h; return x.u;
}

// ---------------- weight repack (verbatim from round 4 — validated) ----------------
__global__ void prep_kernel(const float* __restrict__ Wih0, const float* __restrict__ Whh0,
                            const float* __restrict__ bih0, const float* __restrict__ bhh0,
                            const float* __restrict__ Wih1, const float* __restrict__ Whh1,
                            const float* __restrict__ bih1, const float* __restrict__ bhh1,
                            const float* __restrict__ Wout1, const float* __restrict__ bout1,
                            u16* __restrict__ ws) {
    int i = blockIdx.x * 256 + threadIdx.x;
    if (i >= WS_U16) return;
    int arr, idx = i, KT;
    if (i < OFF_AL0)      { arr = 0; KT = 9; }
    else if (i < OFF_AL1) { arr = 1; idx -= OFF_AL0; KT = 9; }
    else if (i < OFF_AH1) { arr = 2; idx -= OFF_AL1; KT = 17; }
    else                  { arr = 3; idx -= OFF_AH1; KT = 9; }
    const int per_mt = KT * 2 * FR;
    const int mt = idx / per_mt;
    int r = idx - mt * per_mt;
    const int kt = r / (2 * FR);
    r -= kt * 2 * FR;
    const int s    = r >> 9;
    const int f    = r & 511;
    const int lane = f >> 3, j = f & 7;
    const int m    = mt * 16 + (lane & 15);
    const int k_in = ((lane >> 4) << 3) + j;

    float v = 0.f;
    if (arr == 3) {
        if (kt < 8) v = Wout1[m * 256 + kt * 32 + k_in];
        else if (k_in == 0) v = bout1[m];
    } else {
        const int unit = m >> 2, gate = m & 3, row = gate * 256 + unit;
        if (arr == 0) {
            if (kt < 8) v = Wih0[row * 258 + 2 + kt * 32 + k_in];
            else if (k_in == 0) v = bih0[row] + bhh0[row];
        } else if (arr == 1) {
            if (kt < 8) v = Whh0[row * 256 + kt * 32 + k_in];
            else if (k_in < 2) v = Wih0[row * 258 + k_in];
        } else {
            if (kt < 8)         v = Wih1[row * 256 + kt * 32 + k_in];
            else if (kt < 16)   v = Whh1[row * 256 + (kt - 8) * 32 + k_in];
            else if (k_in == 0) v = bih1[row] + bhh1[row];
        }
    }
    _Float16 hi = (_Float16)v;
    ws[i] = (s == 0) ? hbits(hi) : hbits((_Float16)(v - (float)hi));
}

// ---------------- helpers ----------------
__device__ __forceinline__ f32x4 MF(f16x8 a, f16x8 b, f32x4 c) {
    return __builtin_amdgcn_mfma_f32_16x16x32_f16(a, b, c, 0, 0, 0);
}
__device__ __forceinline__ float sigm(float x) { return 1.f / (1.f + __expf(-x)); }
__device__ __forceinline__ float tanh_(float x) {
    float e = __expf(-2.f * fabsf(x));
    float r = (1.f - e) / (1.f + e);
    return copysignf(r, x);
}
__device__ __forceinline__ float lstm_out(f32x4 g, float& c) {
    float iv = sigm(g[0]), fv = sigm(g[1]), gv = tanh_(g[2]), ov = sigm(g[3]);
    c = fmaf(fv, c, iv * gv);
    return ov * tanh_(c);
}

// coherent (L1/L2-bypass) 2-byte store
__device__ __forceinline__ void st16_sc(u16* p, u16 v) {
    asm volatile("global_store_short %0, %1, off sc0 sc1" :: "v"(p), "v"((unsigned)v) : "memory");
}
__device__ __forceinline__ void waitcnt0() {
    asm volatile("s_waitcnt vmcnt(0)" ::: "memory");
}
// coherent flat 32 KB copy global->LDS (2048 uint4, 512 threads x 4)
__device__ __forceinline__ void stage32k(const u16* g, u16* lds, int t) {
    const uint4* s = (const uint4*)g;
    uint4 v0, v1, v2, v3;
    asm volatile("global_load_dwordx4 %0, %1, off sc0 sc1" : "=v"(v0) : "v"(s + t));
    asm volatile("global_load_dwordx4 %0, %1, off sc0 sc1" : "=v"(v1) : "v"(s + t + 512));
    asm volatile("global_load_dwordx4 %0, %1, off sc0 sc1" : "=v"(v2) : "v"(s + t + 1024));
    asm volatile("global_load_dwordx4 %0, %1, off sc0 sc1" : "=v"(v3) : "v"(s + t + 1536));
    waitcnt0();
    __builtin_amdgcn_sched_barrier(0);
    uint4* d = (uint4*)lds;
    d[t] = v0; d[t + 512] = v1; d[t + 1024] = v2; d[t + 1536] = v3;
}
__device__ __forceinline__ void spin_ge(int* p, int target) {
    while (__hip_atomic_load(p, __ATOMIC_RELAXED, __HIP_MEMORY_SCOPE_AGENT) < target)
        __builtin_amdgcn_s_sleep(1);
}
__device__ __forceinline__ size_t hidx(int bc, int par, int layer) {
    return (size_t)((bc * 2 + par) * 2 + layer) * N_HSLAB;
}

// ---------------- main kernel: 256 blocks = 64 bc x 4 uc, 512 thr = 8 waves ----
__global__ __launch_bounds__(512) void lstm_main(
    const float* __restrict__ env, const float* __restrict__ hist,
    const float* __restrict__ goal, const float* __restrict__ cpos,
    const float* __restrict__ Wproj, const float* __restrict__ b_proj,
    const float* __restrict__ Wout2, const float* __restrict__ b_out2,
    u16* __restrict__ wsu, float* __restrict__ out) {

    __shared__ __align__(16) unsigned char smem[98304];
    u16*   Bst   = (u16*)smem;                    // 64 KB: B-frag stage (16 kt slots)
    float* xbuf  = (float*)smem;                  // prologue overlay [386][32]
    unsigned char* regB = smem + 65536;           // 32 KB region
    float* ctxL  = (float*)regB;                  // prologue [256][32] f32
    u16*   posF  = (u16*)regB;                    // steady [s2][nt2][512] = 4 KB
    u16*   onesF = (u16*)(regB + 4096);           // [s2][512] = 2 KB
    float* mlpL  = (float*)(regB + 8192);         // [32][68] f32 = 8704 B

    const int t  = threadIdx.x;
    const int w  = t >> 6;
    const int l  = t & 63;
    const int bc = (int)blockIdx.x >> 2;
    const int uc = (int)blockIdx.x & 3;           // one uc per XCD (bid%8 -> XCD)
    const int row0 = bc * 32;

    u16* Hb = wsu + OFF_H;
    int* flags = (int*)(wsu + OFF_FLG);
    int* f1 = flags + (bc * 2 + 0) * 4;
    int* f2 = flags + (bc * 2 + 1) * 4;

    // per-wave A-fragment bases (mt pair {2w, 2w+1} within uc slice)
    const u16* AG0w = wsu + OFF_AG0 + (size_t)(uc * 16 + 2 * w) * (9 * 1024)  + l * 8;
    const u16* A0w  = wsu + OFF_AL0 + (size_t)(uc * 16 + 2 * w) * (9 * 1024)  + l * 8;
    const u16* A1w  = wsu + OFF_AL1 + (size_t)(uc * 16 + 2 * w) * (17 * 1024) + l * 8;
    const u16* AHw  = wsu + OFF_AH1 + (size_t)(w & 3) * (9 * 1024) + l * 8;
    const int  hn   = w >> 2;                     // head nt for this wave

    // ---- P1: stage ctx_in [k][r] ----
    for (int idx = t; idx < 386 * 32; idx += 512) {
        int r = idx & 31, k = idx >> 5;
        int gr = row0 + r; float v;
        if (k < 256)      v = env[gr * 256 + k];
        else if (k < 384) v = hist[gr * 128 + (k - 256)];
        else              v = goal[gr * 2 + (k - 384)];
        xbuf[k * 32 + r] = v;
    }
    __syncthreads();

    // ---- P2: context fp32 (full 256 units x 32 rows) ----
    {
        const int u = t & 255, rh = t >> 8;
        float acc[16];
        float bp = b_proj[u];
#pragma unroll
        for (int rr = 0; rr < 16; ++rr) acc[rr] = bp;
        for (int k = 0; k < 386; ++k) {
            float wv = Wproj[u * 386 + k];
            const float* xr = &xbuf[k * 32 + rh * 16];
#pragma unroll
            for (int rr = 0; rr < 16; ++rr) acc[rr] = fmaf(xr[rr], wv, acc[rr]);
        }
#pragma unroll
        for (int rr = 0; rr < 16; ++rr) ctxL[u * 32 + rh * 16 + rr] = acc[rr];
    }
    __syncthreads();

    // ---- P3: write own uc-slice of h1(-1), h2(-1) slabs (parity 1) ----
    for (int idx = t; idx < 8192; idx += 512) {
        int layer = idx >> 12;
        int j2 = idx & 4095;
        int f = j2 & 511, nt = (j2 >> 9) & 1, sb = (j2 >> 10) & 1, kl = j2 >> 11;
        int lane = f >> 3, j = f & 7;
        int k_in = ((lane >> 4) << 3) + j;
        int Ug = uc * 64 + kl * 32 + k_in;
        float v = ctxL[Ug * 32 + nt * 16 + (lane & 15)];
        _Float16 hi = (_Float16)v;
        u16 val = sb ? hbits((_Float16)(v - (float)hi)) : hbits(hi);
        int kt = uc * 2 + kl;
        st16_sc(Hb + hidx(bc, 1, layer) + ((kt * 2 + sb) * 2 + nt) * 512 + f, val);
    }
    waitcnt0();
    __syncthreads();
    if (t == 0) {
        __hip_atomic_store(&f1[uc], 0, __ATOMIC_RELAXED, __HIP_MEMORY_SCOPE_AGENT);
        __hip_atomic_store(&f2[uc], 0, __ATOMIC_RELAXED, __HIP_MEMORY_SCOPE_AGENT);
    }
    __syncthreads();   // ctxL reads done -> regB reusable

    // ---- P4: init posF + onesF ----
    for (int idx = t; idx < 2048; idx += 512) {
        int f = idx & 511, nt = (idx >> 9) & 1, sb = idx >> 10;
        int lane = f >> 3, j = f & 7;
        int k_in = ((lane >> 4) << 3) + j;
        u16 val = 0;
        if (k_in < 2) {
            float pv = cpos[(row0 + nt * 16 + (lane & 15)) * 2 + k_in];
            _Float16 hi = (_Float16)pv;
            val = sb ? hbits((_Float16)(pv - (float)hi)) : hbits(hi);
        }
        posF[(sb * 2 + nt) * 512 + f] = val;
    }
    for (int idx = t; idx < 1024; idx += 512) {
        int f = idx & 511, sb = idx >> 9;
        int lane = f >> 3, j = f & 7;
        int k_in = ((lane >> 4) << 3) + j;
        onesF[sb * 512 + f] = (sb == 0 && k_in == 0) ? hbits((_Float16)1.0f) : (u16)0;
    }
    __syncthreads();

    // ---- P5: G0c = AG0 x ctx-frags (+bias via ones) ----
    if (t < 4) spin_ge(&f1[t], 0);
    __syncthreads();
    stage32k(Hb + hidx(bc, 1, 0), Bst, t);
    __syncthreads();

    f32x4 G000 = {0,0,0,0}, G001 = {0,0,0,0}, G010 = {0,0,0,0}, G011 = {0,0,0,0};
#pragma unroll
    for (int kt = 0; kt < 8; ++kt) {
        f16x8 bh0 = *(const f16x8*)&Bst[((kt*2+0)*2+0)*512 + l*8];
        f16x8 bh1 = *(const f16x8*)&Bst[((kt*2+0)*2+1)*512 + l*8];
        f16x8 bl0 = *(const f16x8*)&Bst[((kt*2+1)*2+0)*512 + l*8];
        f16x8 bl1 = *(const f16x8*)&Bst[((kt*2+1)*2+1)*512 + l*8];
        const u16* p0 = AG0w + kt * 1024;
        const u16* p1 = AG0w + (9 + kt) * 1024;
        f16x8 ah0 = *(const f16x8*)p0, al0 = *(const f16x8*)(p0 + 512);
        f16x8 ah1 = *(const f16x8*)p1, al1 = *(const f16x8*)(p1 + 512);
        G000 = MF(ah0,bh0,G000); G000 = MF(ah0,bl0,G000); G000 = MF(al0,bh0,G000);
        G001 = MF(ah0,bh1,G001); G001 = MF(ah0,bl1,G001); G001 = MF(al0,bh1,G001);
        G010 = MF(ah1,bh0,G010); G010 = MF(ah1,bl0,G010); G010 = MF(al1,bh0,G010);
        G011 = MF(ah1,bh1,G011); G011 = MF(ah1,bl1,G011); G011 = MF(al1,bh1,G011);
    }
    {   // bias column
        f16x8 bh = *(const f16x8*)&onesF[l*8];
        f16x8 bl = *(const f16x8*)&onesF[512 + l*8];
        const u16* p0 = AG0w + 8 * 1024;
        const u16* p1 = AG0w + (9 + 8) * 1024;
        f16x8 ah0 = *(const f16x8*)p0, al0 = *(const f16x8*)(p0 + 512);
        f16x8 ah1 = *(const f16x8*)p1, al1 = *(const f16x8*)(p1 + 512);
        G000 = MF(ah0,bh,G000); G000 = MF(ah0,bl,G000); G000 = MF(al0,bh,G000);
        G001 = MF(ah0,bh,G001); G001 = MF(ah0,bl,G001); G001 = MF(al0,bh,G001);
        G010 = MF(ah1,bh,G010); G010 = MF(ah1,bl,G010); G010 = MF(al1,bh,G010);
        G011 = MF(ah1,bh,G011); G011 = MF(ah1,bl,G011); G011 = MF(al1,bh,G011);
    }

    float c1[2][2] = {{0,0},{0,0}}, c2[2][2] = {{0,0},{0,0}};

    // ================= time loop =================
    for (int s = 0; s < Tst; ++s) {
        const int par = s & 1;

        // ===== L0: gates0 = G0c + Whh0@h1(s-1) + Wpos@pos =====
        if (t < 4) spin_ge(&f1[t], s);
        __syncthreads();                               // also: Bst reads of prev phase done
        stage32k(Hb + hidx(bc, par ^ 1, 0), Bst, t);   // h1(s-1)
        __syncthreads();
        {
            f32x4 a00 = G000, a01 = G001, a10 = G010, a11 = G011;
#pragma unroll
            for (int kt = 0; kt < 8; ++kt) {
                f16x8 bh0 = *(const f16x8*)&Bst[((kt*2+0)*2+0)*512 + l*8];
                f16x8 bh1 = *(const f16x8*)&Bst[((kt*2+0)*2+1)*512 + l*8];
                f16x8 bl0 = *(const f16x8*)&Bst[((kt*2+1)*2+0)*512 + l*8];
                f16x8 bl1 = *(const f16x8*)&Bst[((kt*2+1)*2+1)*512 + l*8];
                const u16* p0 = A0w + kt * 1024;
                const u16* p1 = A0w + (9 + kt) * 1024;
                f16x8 ah0 = *(const f16x8*)p0, al0 = *(const f16x8*)(p0 + 512);
                f16x8 ah1 = *(const f16x8*)p1, al1 = *(const f16x8*)(p1 + 512);
                a00 = MF(ah0,bh0,a00); a00 = MF(ah0,bl0,a00); a00 = MF(al0,bh0,a00);
                a01 = MF(ah0,bh1,a01); a01 = MF(ah0,bl1,a01); a01 = MF(al0,bh1,a01);
                a10 = MF(ah1,bh0,a10); a10 = MF(ah1,bl0,a10); a10 = MF(al1,bh0,a10);
                a11 = MF(ah1,bh1,a11); a11 = MF(ah1,bl1,a11); a11 = MF(al1,bh1,a11);
            }
            {   // pos column (kt 8)
                f16x8 bh0 = *(const f16x8*)&posF[(0*2+0)*512 + l*8];
                f16x8 bh1 = *(const f16x8*)&posF[(0*2+1)*512 + l*8];
                f16x8 bl0 = *(const f16x8*)&posF[(1*2+0)*512 + l*8];
                f16x8 bl1 = *(const f16x8*)&posF[(1*2+1)*512 + l*8];
                const u16* p0 = A0w + 8 * 1024;
                const u16* p1 = A0w + (9 + 8) * 1024;
                f16x8 ah0 = *(const f16x8*)p0, al0 = *(const f16x8*)(p0 + 512);
                f16x8 ah1 = *(const f16x8*)p1, al1 = *(const f16x8*)(p1 + 512);
                a00 = MF(ah0,bh0,a00); a00 = MF(ah0,bl0,a00); a00 = MF(al0,bh0,a00);
                a01 = MF(ah0,bh1,a01); a01 = MF(ah0,bl1,a01); a01 = MF(al0,bh1,a01);
                a10 = MF(ah1,bh0,a10); a10 = MF(ah1,bl0,a10); a10 = MF(al1,bh0,a10);
                a11 = MF(ah1,bh1,a11); a11 = MF(ah1,bl1,a11); a11 = MF(al1,bh1,a11);
            }
            float h1n[2][2];
            h1n[0][0] = lstm_out(a00, c1[0][0]);
            h1n[0][1] = lstm_out(a01, c1[0][1]);
            h1n[1][0] = lstm_out(a10, c1[1][0]);
            h1n[1][1] = lstm_out(a11, c1[1][1]);
            // write own slice of h1(s)
            u16* slab = Hb + hidx(bc, par, 0);
#pragma unroll
            for (int mm = 0; mm < 2; ++mm) {
                const int U  = (2 * w + mm) * 4 + (l >> 4);
                const int kt = uc * 2 + (U >> 5);
                const int ki = U & 31;
                const int f  = ((l & 15) + 16 * (ki >> 3)) * 8 + (ki & 7);
#pragma unroll
                for (int nt = 0; nt < 2; ++nt) {
                    float v = h1n[mm][nt];
                    _Float16 hi = (_Float16)v;
                    st16_sc(slab + ((kt*2+0)*2+nt)*512 + f, hbits(hi));
                    st16_sc(slab + ((kt*2+1)*2+nt)*512 + f, hbits((_Float16)(v - (float)hi)));
                }
            }
        }
        waitcnt0();
        __syncthreads();
        if (t == 0) __hip_atomic_store(&f1[uc], s + 1, __ATOMIC_RELAXED, __HIP_MEMORY_SCOPE_AGENT);

        // ===== L1: gates1 = bias + Wih1@h1(s) + Whh1@h2(s-1) =====
        if (t < 4)      spin_ge(&f1[t], s + 1);
        else if (t < 8) spin_ge(&f2[t - 4], s);
        __syncthreads();
        stage32k(Hb + hidx(bc, par, 0),     Bst,         t);   // h1(s)   -> kt 0..7
        stage32k(Hb + hidx(bc, par ^ 1, 1), Bst + 16384, t);   // h2(s-1) -> kt 8..15
        __syncthreads();
        {
            f32x4 a00 = {0,0,0,0}, a01 = {0,0,0,0}, a10 = {0,0,0,0}, a11 = {0,0,0,0};
#pragma unroll
            for (int kt = 0; kt < 16; ++kt) {
                f16x8 bh0 = *(const f16x8*)&Bst[((kt*2+0)*2+0)*512 + l*8];
                f16x8 bh1 = *(const f16x8*)&Bst[((kt*2+0)*2+1)*512 + l*8];
                f16x8 bl0 = *(const f16x8*)&Bst[((kt*2+1)*2+0)*512 + l*8];
                f16x8 bl1 = *(const f16x8*)&Bst[((kt*2+1)*2+1)*512 + l*8];
                const u16* p0 = A1w + kt * 1024;
                const u16* p1 = A1w + (17 + kt) * 1024;
                f16x8 ah0 = *(const f16x8*)p0, al0 = *(const f16x8*)(p0 + 512);
                f16x8 ah1 = *(const f16x8*)p1, al1 = *(const f16x8*)(p1 + 512);
                a00 = MF(ah0,bh0,a00); a00 = MF(ah0,bl0,a00); a00 = MF(al0,bh0,a00);
                a01 = MF(ah0,bh1,a01); a01 = MF(ah0,bl1,a01); a01 = MF(al0,bh1,a01);
                a10 = MF(ah1,bh0,a10); a10 = MF(ah1,bl0,a10); a10 = MF(al1,bh0,a10);
                a11 = MF(ah1,bh1,a11); a11 = MF(ah1,bl1,a11); a11 = MF(al1,bh1,a11);
            }
            {   // bias column (kt 16)
                f16x8 bh = *(const f16x8*)&onesF[l*8];
                f16x8 bl = *(const f16x8*)&onesF[512 + l*8];
                const u16* p0 = A1w + 16 * 1024;
                const u16* p1 = A1w + (17 + 16) * 1024;
                f16x8 ah0 = *(const f16x8*)p0, al0 = *(const f16x8*)(p0 + 512);
                f16x8 ah1 = *(const f16x8*)p1, al1 = *(const f16x8*)(p1 + 512);
                a00 = MF(ah0,bh,a00); a00 = MF(ah0,bl,a00); a00 = MF(al0,bh,a00);
                a01 = MF(ah0,bh,a01); a01 = MF(ah0,bl,a01); a01 = MF(al0,bh,a01);
                a10 = MF(ah1,bh,a10); a10 = MF(ah1,bl,a10); a10 = MF(al1,bh,a10);
                a11 = MF(ah1,bh,a11); a11 = MF(ah1,bl,a11); a11 = MF(al1,bh,a11);
            }
            float h2n[2][2];
            h2n[0][0] = lstm_out(a00, c2[0][0]);
            h2n[0][1] = lstm_out(a01, c2[0][1]);
            h2n[1][0] = lstm_out(a10, c2[1][0]);
            h2n[1][1] = lstm_out(a11, c2[1][1]);
            u16* slab = Hb + hidx(bc, par, 1);
#pragma unroll
            for (int mm = 0; mm < 2; ++mm) {
                const int U  = (2 * w + mm) * 4 + (l >> 4);
                const int kt = uc * 2 + (U >> 5);
                const int ki = U & 31;
                const int f  = ((l & 15) + 16 * (ki >> 3)) * 8 + (ki & 7);
#pragma unroll
                for (int nt = 0; nt < 2; ++nt) {
                    float v = h2n[mm][nt];
                    _Float16 hi = (_Float16)v;
                    st16_sc(slab + ((kt*2+0)*2+nt)*512 + f, hbits(hi));
                    st16_sc(slab + ((kt*2+1)*2+nt)*512 + f, hbits((_Float16)(v - (float)hi)));
                }
            }
        }
        waitcnt0();
        __syncthreads();
        if (t == 0) __hip_atomic_store(&f2[uc], s + 1, __ATOMIC_RELAXED, __HIP_MEMORY_SCOPE_AGENT);

        // ===== head: mlp = relu(h2(s) @ Wout1^T + b_out1); pred; pos feedback =====
        if (t < 4) spin_ge(&f2[t], s + 1);
        __syncthreads();
        stage32k(Hb + hidx(bc, par, 1), Bst, t);   // h2(s)
        __syncthreads();
        {
            f32x4 pv = {0,0,0,0};
#pragma unroll
            for (int kt = 0; kt < 8; ++kt) {
                f16x8 bh = *(const f16x8*)&Bst[((kt*2+0)*2+hn)*512 + l*8];
                f16x8 bl = *(const f16x8*)&Bst[((kt*2+1)*2+hn)*512 + l*8];
                const u16* p = AHw + kt * 1024;
                f16x8 ah = *(const f16x8*)p, al = *(const f16x8*)(p + 512);
                pv = MF(ah, bh, pv); pv = MF(ah, bl, pv); pv = MF(al, bh, pv);
            }
            {   // b_out1 column
                f16x8 bh = *(const f16x8*)&onesF[l*8];
                f16x8 bl = *(const f16x8*)&onesF[512 + l*8];
                const u16* p = AHw + 8 * 1024;
                f16x8 ah = *(const f16x8*)p, al = *(const f16x8*)(p + 512);
                pv = MF(ah, bh, pv); pv = MF(ah, bl, pv); pv = MF(al, bh, pv);
            }
#pragma unroll
            for (int r = 0; r < 4; ++r) pv[r] = fmaxf(pv[r], 0.f);
            const int mrow = hn * 16 + (l & 15);
            *(f32x4*)&mlpL[mrow * 68 + (w & 3) * 16 + (l >> 4) * 4] = pv;
        }
        __syncthreads();
        if (t < 64) {
            const int r = t >> 1, o = t & 1;
            float a = b_out2[o];
#pragma unroll 8
            for (int k = 0; k < 64; ++k) a = fmaf(mlpL[r * 68 + k], Wout2[o * 64 + k], a);
            if (uc == 0) out[((size_t)(row0 + r) * Tst + s) * 2 + o] = a;
            _Float16 hi = (_Float16)a;
            posF[(0 * 2 + (r >> 4)) * 512 + (r & 15) * 8 + o] = hbits(hi);
            posF[(2 + (r >> 4)) * 512 + (r & 15) * 8 + o] = hbits((_Float16)(a - (float)hi));
        }
        // next L0's stage-barrier orders posF/Bst reuse
    }
}

// ---------------- launch ----------------
extern "C" void kernel_launch(void* const* d_in, const int* in_sizes, int n_in,
                              void* d_out, int out_size, void* d_ws, size_t ws_size,
                              hipStream_t stream) {
    const float* env   = (const float*)d_in[0];
    const float* hist  = (const float*)d_in[1];
    const float* goal  = (const float*)d_in[2];
    const float* cpos  = (const float*)d_in[3];
    const float* Wproj = (const float*)d_in[4];
    const float* bproj = (const float*)d_in[5];
    const float* Wih0  = (const float*)d_in[6];
    const float* Whh0  = (const float*)d_in[7];
    const float* bih0  = (const float*)d_in[8];
    const float* bhh0  = (const float*)d_in[9];
    const float* Wih1  = (const float*)d_in[10];
    const float* Whh1  = (const float*)d_in[11];
    const float* bih1  = (const float*)d_in[12];
    const float* bhh1  = (const float*)d_in[13];
    const float* Wout1 = (const float*)d_in[14];
    const float* bout1 = (const float*)d_in[15];
    const float* Wout2 = (const float*)d_in[16];
    const float* bout2 = (const float*)d_in[17];

    if (ws_size < WS_BYTES) return;   // need ~12.5 MB scratch
    u16* wsu = (u16*)d_ws;

    hipMemsetAsync((char*)d_ws + (size_t)OFF_FLG * 2, 0xFF,
                   (size_t)N_FLAGS * sizeof(int), stream);

    prep_kernel<<<(WS_U16 + 255) / 256, 256, 0, stream>>>(
        Wih0, Whh0, bih0, bhh0, Wih1, Whh1, bih1, bhh1, Wout1, bout1, wsu);

    lstm_main<<<256, 512, 0, stream>>>(
        env, hist, goal, cpos, Wproj, bproj, Wout2, bout2, wsu, (float*)d_out);
}